// Round 1
// 274.291 us; speedup vs baseline: 1.1311x; 1.1311x over previous
//
#include <hip/hip_runtime.h>

// GraphSAGE 2-layer: logits = meanAgg(relu(meanAgg(x@W1)) @ W2)
// N=100000, E=1600000, D_IN=128, D_H=128, D_OUT=64, fp32 in/out.
//
// R2: parallel scan. R3: agg x4 unroll. R4: FAILED 1024-thr gemm (spills).
// R5: gemm W from global. R6: counting-sort CSR build (no global atomics).
// R7: bf16 gather buffers, x8 unroll. R8: parallel HT scan.
// R9: MFMA gemms; k_prep transposes W to bf16 [n][k]; agg1 emits bf16.
// R10: wide gathers in agg. agg1: dwordx4, 16 lanes/row -> 4 neighbors per
//      load instr (was 16 loads/row); agg2: 8 lanes/row -> 8 neighbors per
//      load. 32-bit voffset addressing. shfl_xor butterfly combines the
//      lane-group partials; group 0 stores one coalesced dwordx4.

#define DIN 128
#define DH 128
#define DOUT 64

#define BSH 9                    // 512 rows per bucket
#define COLB 17                  // col fits 17 bits (N=100000 < 2^17)
#define COLM ((1 << COLB) - 1)
#define LRM ((1 << BSH) - 1)
#define CHUNK 4096               // edges per hist/part block
#define CH_PT 16                 // edges per thread

typedef __attribute__((ext_vector_type(8))) short short8;
typedef __attribute__((ext_vector_type(4))) float floatx4;

__device__ __forceinline__ unsigned bfpack(float a, float b) {
    unsigned ua = __float_as_uint(a);
    unsigned ub = __float_as_uint(b);
    ua += 0x7fffu + ((ua >> 16) & 1u);
    ub += 0x7fffu + ((ub >> 16) & 1u);
    return (ua >> 16) | (ub & 0xffff0000u);
}
__device__ __forceinline__ unsigned short bf1(float a) {
    unsigned u = __float_as_uint(a);
    u += 0x7fffu + ((u >> 16) & 1u);
    return (unsigned short)(u >> 16);
}

// unpack a dwordx4 of 8 bf16 and accumulate into 8 fp32
__device__ __forceinline__ void acc8(float* a, uint4 v) {
    a[0] += __uint_as_float(v.x << 16);
    a[1] += __uint_as_float(v.x & 0xffff0000u);
    a[2] += __uint_as_float(v.y << 16);
    a[3] += __uint_as_float(v.y & 0xffff0000u);
    a[4] += __uint_as_float(v.z << 16);
    a[5] += __uint_as_float(v.z & 0xffff0000u);
    a[6] += __uint_as_float(v.w << 16);
    a[7] += __uint_as_float(v.w & 0xffff0000u);
}

// ---------------- weight prep: fp32 [k][n] -> bf16 [n][k] ----------------
__global__ __launch_bounds__(256) void k_prep(const float* __restrict__ W1,
                                              const float* __restrict__ W2,
                                              unsigned short* __restrict__ Wt1,
                                              unsigned short* __restrict__ Wt2) {
    int idx = blockIdx.x * 256 + threadIdx.x;
    if (idx < 128 * 128) {
        int k = idx >> 7, nn = idx & 127;
        Wt1[nn * 128 + k] = bf1(W1[idx]);
    }
    int i2 = idx - 128 * 128;
    if (i2 >= 0 && i2 < 128 * 64) {
        int k = i2 >> 6, nn = i2 & 63;
        Wt2[nn * 128 + k] = bf1(W2[i2]);
    }
}

// ---------------- CSR build (counting sort) ----------------

__global__ __launch_bounds__(256) void k_hist(const int* __restrict__ row,
                                              int* __restrict__ HT,
                                              int E, int nb, int nch) {
    __shared__ int h[512];
    int t = threadIdx.x, c = blockIdx.x;
    for (int i = t; i < nb; i += 256) h[i] = 0;
    __syncthreads();
    int base = c * CHUNK;
#pragma unroll
    for (int i = 0; i < CH_PT; ++i) {
        int e = base + i * 256 + t;
        if (e < E) atomicAdd(&h[row[e] >> BSH], 1);
    }
    __syncthreads();
    for (int i = t; i < nb; i += 256) HT[(size_t)i * nch + c] = h[i];
}

__global__ __launch_bounds__(256) void k_hscan_row(int* __restrict__ HT,
                                                   int* __restrict__ bsum,
                                                   int nch) {
    __shared__ int sh[256];
    int b = blockIdx.x, t = threadIdx.x;
    int carry = 0;
    for (int tile = 0; tile < nch; tile += 256) {
        int idx = tile + t;
        int v = (idx < nch) ? HT[(size_t)b * nch + idx] : 0;
        sh[t] = v;
        __syncthreads();
        for (int d = 1; d < 256; d <<= 1) {
            int u = (t >= d) ? sh[t - d] : 0;
            __syncthreads();
            sh[t] += u;
            __syncthreads();
        }
        if (idx < nch) HT[(size_t)b * nch + idx] = carry + sh[t] - v;
        carry += sh[255];
        __syncthreads();
    }
    if (t == 0) bsum[b] = carry;
}

__global__ __launch_bounds__(256) void k_hscan_base(const int* __restrict__ bsum,
                                                    int* __restrict__ bucketBase,
                                                    int nb, int E) {
    __shared__ int sh[256];
    int t = threadIdx.x;
    int v = (t < nb) ? bsum[t] : 0;
    sh[t] = v;
    __syncthreads();
    for (int d = 1; d < 256; d <<= 1) {
        int u = (t >= d) ? sh[t - d] : 0;
        __syncthreads();
        sh[t] += u;
        __syncthreads();
    }
    if (t < nb) bucketBase[t] = sh[t] - v;
    if (t == 0) bucketBase[nb] = E;
}

__global__ __launch_bounds__(256) void k_part(const int* __restrict__ row,
                                              const int* __restrict__ col,
                                              const int* __restrict__ HT,
                                              const int* __restrict__ bucketBase,
                                              int* __restrict__ packed,
                                              int E, int nb, int nch) {
    __shared__ int cur[512];
    int t = threadIdx.x, c = blockIdx.x;
    for (int i = t; i < nb; i += 256)
        cur[i] = HT[(size_t)i * nch + c] + bucketBase[i];
    __syncthreads();
    int base = c * CHUNK;
#pragma unroll
    for (int i = 0; i < CH_PT; ++i) {
        int e = base + i * 256 + t;
        if (e < E) {
            int r = row[e], cc = col[e];
            int b = r >> BSH;
            int pos = atomicAdd(&cur[b], 1);
            packed[pos] = ((r & LRM) << COLB) | cc;
        }
    }
}

__global__ __launch_bounds__(256) void k_build(const int* __restrict__ packed,
                                               const int* __restrict__ bucketBase,
                                               int* __restrict__ csr,
                                               int* __restrict__ offs,
                                               int* __restrict__ degc,
                                               float* __restrict__ invdeg,
                                               int N, int nb) {
    __shared__ int hist[512], scn[512], part[256];
    int t = threadIdx.x, b = blockIdx.x;
    int lo = bucketBase[b], hi = bucketBase[b + 1];
    int base_row = b << BSH;
    int nloc = N - base_row; if (nloc > 512) nloc = 512;
    hist[t] = 0; hist[t + 256] = 0;
    __syncthreads();
    for (int e = lo + t; e < hi; e += 256)
        atomicAdd(&hist[packed[e] >> COLB], 1);
    __syncthreads();
    int a = hist[2 * t], b2 = hist[2 * t + 1];
    part[t] = a + b2;
    __syncthreads();
    for (int d = 1; d < 256; d <<= 1) {
        int v = (t >= d) ? part[t - d] : 0;
        __syncthreads();
        part[t] += v;
        __syncthreads();
    }
    int bp = (t == 0) ? 0 : part[t - 1];
    scn[2 * t] = bp;
    scn[2 * t + 1] = bp + a;
    __syncthreads();
    for (int i = t; i < nloc; i += 256) {
        int r = base_row + i;
        offs[r] = lo + scn[i];
        int d = hist[i];
        degc[r] = d;
        invdeg[r] = 1.0f / (float)d;
    }
    __syncthreads();
    for (int e = lo + t; e < hi; e += 256) {
        int p = packed[e];
        int pos = lo + atomicAdd(&scn[p >> COLB], 1);
        csr[pos] = p & COLM;
    }
}

// ---------------- MFMA GEMMs ----------------

// h1b[n,128](bf16) = X @ W1. 256 thr, 64-row block; wave w: rows w*16..+15.
__global__ __launch_bounds__(256) void k_gemm1(const float* __restrict__ X,
                                               const unsigned short* __restrict__ Wt,
                                               unsigned short* __restrict__ H1b, int n) {
    __shared__ unsigned short xs[64][136];    // pitch 272B: 2-way-bank-safe b128
    __shared__ unsigned short wt[128][136];
    int tid = threadIdx.x;
    int r0 = blockIdx.x * 64;

    for (int i = tid; i < 64 * 32; i += 256) {
        int r = i >> 5, c4 = i & 31;
        float4 v = make_float4(0.f, 0.f, 0.f, 0.f);
        if (r0 + r < n) v = ((const float4*)X)[(size_t)(r0 + r) * 32 + c4];
        *(uint2*)&xs[r][c4 * 4] = make_uint2(bfpack(v.x, v.y), bfpack(v.z, v.w));
    }
    for (int i = tid; i < 128 * 16; i += 256) {
        int r = i >> 4, c = i & 15;
        *(uint4*)&wt[r][c * 8] = ((const uint4*)Wt)[r * 16 + c];
    }
    __syncthreads();

    int w = tid >> 6, lane = tid & 63;
    int ml = lane & 15, q = lane >> 4;
    floatx4 acc[8];
#pragma unroll
    for (int t = 0; t < 8; ++t) acc[t] = (floatx4)(0.f);

#pragma unroll
    for (int kc = 0; kc < 4; ++kc) {
        short8 af = *(const short8*)&xs[w * 16 + ml][kc * 32 + q * 8];
#pragma unroll
        for (int nt = 0; nt < 8; ++nt) {
            short8 bf = *(const short8*)&wt[nt * 16 + ml][kc * 32 + q * 8];
            acc[nt] = __builtin_amdgcn_mfma_f32_16x16x32_bf16(af, bf, acc[nt], 0, 0, 0);
        }
    }
#pragma unroll
    for (int nt = 0; nt < 8; ++nt)
#pragma unroll
        for (int r = 0; r < 4; ++r) {
            int rr = r0 + w * 16 + q * 4 + r;
            if (rr < n)
                H1b[(size_t)rr * 128 + nt * 16 + ml] = bf1(acc[nt][r]);
        }
}

// h2b[n,64](bf16) = h(bf16) @ W2. Same structure, N=64.
__global__ __launch_bounds__(256) void k_gemm2(const unsigned* __restrict__ Hin,
                                               const unsigned short* __restrict__ Wt,
                                               unsigned short* __restrict__ H2b, int n) {
    __shared__ unsigned short xs[64][136];
    __shared__ unsigned short wt[64][136];
    int tid = threadIdx.x;
    int r0 = blockIdx.x * 64;

    for (int i = tid; i < 64 * 16; i += 256) {
        int r = i >> 4, c = i & 15;
        uint4 v = make_uint4(0u, 0u, 0u, 0u);
        if (r0 + r < n) v = ((const uint4*)Hin)[(size_t)(r0 + r) * 16 + c];
        *(uint4*)&xs[r][c * 8] = v;
    }
    for (int i = tid; i < 64 * 16; i += 256) {
        int r = i >> 4, c = i & 15;
        *(uint4*)&wt[r][c * 8] = ((const uint4*)Wt)[r * 16 + c];
    }
    __syncthreads();

    int w = tid >> 6, lane = tid & 63;
    int ml = lane & 15, q = lane >> 4;
    floatx4 acc[4];
#pragma unroll
    for (int t = 0; t < 4; ++t) acc[t] = (floatx4)(0.f);

#pragma unroll
    for (int kc = 0; kc < 4; ++kc) {
        short8 af = *(const short8*)&xs[w * 16 + ml][kc * 32 + q * 8];
#pragma unroll
        for (int nt = 0; nt < 4; ++nt) {
            short8 bf = *(const short8*)&wt[nt * 16 + ml][kc * 32 + q * 8];
            acc[nt] = __builtin_amdgcn_mfma_f32_16x16x32_bf16(af, bf, acc[nt], 0, 0, 0);
        }
    }
#pragma unroll
    for (int nt = 0; nt < 4; ++nt)
#pragma unroll
        for (int r = 0; r < 4; ++r) {
            int rr = r0 + w * 16 + q * 4 + r;
            if (rr < n)
                H2b[(size_t)rr * 64 + nt * 16 + ml] = bf1(acc[nt][r]);
        }
}

// ---------------- Aggregations ----------------

// agg1: h[row](bf16) = relu((1/deg) * sum h1b[c]), D=128 (row = 16 uint4).
// 16 lanes cover one neighbor row; lane group g = lane>>4 takes neighbor
// i+g -> 4 neighbors per dwordx4 gather. Partials combined via shfl_xor.
__global__ __launch_bounds__(256) void k_agg1(const uint4* __restrict__ H1b,
                                              const int* __restrict__ offs,
                                              const int* __restrict__ degc,
                                              const float* __restrict__ invdeg,
                                              const int* __restrict__ csr,
                                              uint4* __restrict__ Hout, int n) {
    int wave = threadIdx.x >> 6, lane = threadIdx.x & 63;
    int row = blockIdx.x * 4 + wave;
    if (row >= n) return;
    int start = offs[row], d = degc[row];
    int g = lane >> 4;       // neighbor slot 0..3
    int sl = lane & 15;      // 16B segment within row

    float acc[8];
#pragma unroll
    for (int k = 0; k < 8; ++k) acc[k] = 0.f;

    int i = 0;
    for (; i + 8 <= d; i += 8) {
        int c0 = csr[start + i + g];
        int c1 = csr[start + i + 4 + g];
        uint4 v0 = H1b[((unsigned)c0 << 4) + sl];
        uint4 v1 = H1b[((unsigned)c1 << 4) + sl];
        acc8(acc, v0);
        acc8(acc, v1);
    }
    for (; i < d; i += 4) {
        int j = i + g;
        uint4 v = make_uint4(0u, 0u, 0u, 0u);
        if (j < d) {
            int c = csr[start + j];
            v = H1b[((unsigned)c << 4) + sl];
        }
        acc8(acc, v);
    }

#pragma unroll
    for (int k = 0; k < 8; ++k) {
        acc[k] += __shfl_xor(acc[k], 16);
        acc[k] += __shfl_xor(acc[k], 32);
    }

    if (g == 0) {
        float inv = invdeg[row];
#pragma unroll
        for (int k = 0; k < 8; ++k) acc[k] = fmaxf(acc[k] * inv, 0.f);
        uint4 o;
        o.x = bfpack(acc[0], acc[1]);
        o.y = bfpack(acc[2], acc[3]);
        o.z = bfpack(acc[4], acc[5]);
        o.w = bfpack(acc[6], acc[7]);
        Hout[(size_t)row * 16 + sl] = o;
    }
}

// agg2: Out[row](fp32) = (1/deg) * sum h2b[c], D=64 (row = 8 uint4).
// 8 lanes cover one neighbor row; lane group g = lane>>3 takes neighbor
// i+g -> 8 neighbors per dwordx4 gather.
__global__ __launch_bounds__(256) void k_agg2(const uint4* __restrict__ H2b,
                                              const int* __restrict__ offs,
                                              const int* __restrict__ degc,
                                              const float* __restrict__ invdeg,
                                              const int* __restrict__ csr,
                                              float* __restrict__ Out, int n) {
    int wave = threadIdx.x >> 6, lane = threadIdx.x & 63;
    int row = blockIdx.x * 4 + wave;
    if (row >= n) return;
    int start = offs[row], d = degc[row];
    int g = lane >> 3;       // neighbor slot 0..7
    int sl = lane & 7;       // 16B segment within row

    float acc[8];
#pragma unroll
    for (int k = 0; k < 8; ++k) acc[k] = 0.f;

    int i = 0;
    for (; i + 16 <= d; i += 16) {
        int c0 = csr[start + i + g];
        int c1 = csr[start + i + 8 + g];
        uint4 v0 = H2b[((unsigned)c0 << 3) + sl];
        uint4 v1 = H2b[((unsigned)c1 << 3) + sl];
        acc8(acc, v0);
        acc8(acc, v1);
    }
    for (; i < d; i += 8) {
        int j = i + g;
        uint4 v = make_uint4(0u, 0u, 0u, 0u);
        if (j < d) {
            int c = csr[start + j];
            v = H2b[((unsigned)c << 3) + sl];
        }
        acc8(acc, v);
    }

#pragma unroll
    for (int k = 0; k < 8; ++k) {
        acc[k] += __shfl_xor(acc[k], 8);
        acc[k] += __shfl_xor(acc[k], 16);
        acc[k] += __shfl_xor(acc[k], 32);
    }

    if (g == 0) {
        float inv = invdeg[row];
        float4 o0, o1;
        o0.x = acc[0] * inv; o0.y = acc[1] * inv;
        o0.z = acc[2] * inv; o0.w = acc[3] * inv;
        o1.x = acc[4] * inv; o1.y = acc[5] * inv;
        o1.z = acc[6] * inv; o1.w = acc[7] * inv;
        ((float4*)Out)[(size_t)row * 16 + sl * 2]     = o0;
        ((float4*)Out)[(size_t)row * 16 + sl * 2 + 1] = o1;
    }
}

extern "C" void kernel_launch(void* const* d_in, const int* in_sizes, int n_in,
                              void* d_out, int out_size, void* d_ws, size_t ws_size,
                              hipStream_t stream) {
    const float* x    = (const float*)d_in[0];
    const float* W1   = (const float*)d_in[1];
    const float* W2   = (const float*)d_in[2];
    const int*   erow = (const int*)d_in[3];
    const int*   ecol = (const int*)d_in[4];
    const int N = in_sizes[0] / DIN;
    const int E = in_sizes[3];

    const int nb  = (N + (1 << BSH) - 1) >> BSH;   // 196 buckets
    const int nch = (E + CHUNK - 1) / CHUNK;       // 391 chunks

    size_t o = 0;
    auto take = [&](size_t nbytes) {
        void* p = (char*)d_ws + o;
        o += (nbytes + 255) & ~(size_t)255;
        return p;
    };
    int*            HT     = (int*)take((size_t)nb * nch * 4);
    int*            bsum   = (int*)take((size_t)nb * 4);
    int*            bbase  = (int*)take((size_t)(nb + 1) * 4);
    int*            packed = (int*)take((size_t)E * 4);
    int*            csr    = (int*)take((size_t)E * 4);
    int*            offs   = (int*)take((size_t)N * 4);
    int*            degc   = (int*)take((size_t)N * 4);
    float*          invdeg = (float*)take((size_t)N * 4);
    unsigned short* Wt1    = (unsigned short*)take(128 * 128 * 2);
    unsigned short* Wt2    = (unsigned short*)take(64 * 128 * 2);
    unsigned*       h1b    = (unsigned*)take((size_t)N * DH * 2);   // bf16
    unsigned*       h      = (unsigned*)take((size_t)N * DH * 2);   // bf16
    unsigned*       h2b    = h1b;   // reuses h1b (dead after agg1)

    k_prep      <<<96,  256, 0, stream>>>(W1, W2, Wt1, Wt2);
    k_hist      <<<nch, 256, 0, stream>>>(erow, HT, E, nb, nch);
    k_hscan_row <<<nb,  256, 0, stream>>>(HT, bsum, nch);
    k_hscan_base<<<1,   256, 0, stream>>>(bsum, bbase, nb, E);
    k_part      <<<nch, 256, 0, stream>>>(erow, ecol, HT, bbase, packed, E, nb, nch);
    k_build     <<<nb,  256, 0, stream>>>(packed, bbase, csr, offs, degc, invdeg, N, nb);
    k_gemm1<<<(N + 63) / 64, 256, 0, stream>>>(x, Wt1, (unsigned short*)h1b, N);
    k_agg1 <<<(N + 3) / 4, 256, 0, stream>>>((const uint4*)h1b, offs, degc, invdeg,
                                             csr, (uint4*)h, N);
    k_gemm2<<<(N + 63) / 64, 256, 0, stream>>>(h, Wt2, (unsigned short*)h2b, N);
    k_agg2 <<<(N + 3) / 4, 256, 0, stream>>>((const uint4*)h2b, offs, degc,
                                             invdeg, csr, (float*)d_out, N);
}

// Round 3
// 268.552 us; speedup vs baseline: 1.1553x; 1.0214x over previous
//
#include <hip/hip_runtime.h>

// GraphSAGE 2-layer: logits = meanAgg(relu(meanAgg(x@W1)) @ W2)
// N=100000, E=1600000, D_IN=128, D_H=128, D_OUT=64, fp32 in/out.
//
// R2: parallel scan. R3: agg x4 unroll. R4: FAILED 1024-thr gemm (spills).
// R5: gemm W from global. R6: counting-sort CSR build (no global atomics).
// R7: bf16 gather buffers, x8 unroll. R8: parallel HT scan.
// R9: MFMA gemms; k_prep transposes W to bf16 [n][k]; agg1 emits bf16.
// R10: wide dwordx4 gathers in agg (4 or 8 neighbors per load instr).
// R11: FAILED: csr row cached in regs + __shfl distribution, but shfl was
//      inside a divergent branch -> ds_bpermute reads from inactive source
//      lanes return 0 -> tail neighbors replaced by row 0.
// R12: fix = shfl hoisted out of the branch (wave-uniform, clamped source
//      lane); only the gather+acc predicated. Keeps R11's index-off-the-
//      critical-path + 16-deep gather pipeline.

#define DIN 128
#define DH 128
#define DOUT 64

#define BSH 9                    // 512 rows per bucket
#define COLB 17                  // col fits 17 bits (N=100000 < 2^17)
#define COLM ((1 << COLB) - 1)
#define LRM ((1 << BSH) - 1)
#define CHUNK 4096               // edges per hist/part block
#define CH_PT 16                 // edges per thread

typedef __attribute__((ext_vector_type(8))) short short8;
typedef __attribute__((ext_vector_type(4))) float floatx4;

__device__ __forceinline__ unsigned bfpack(float a, float b) {
    unsigned ua = __float_as_uint(a);
    unsigned ub = __float_as_uint(b);
    ua += 0x7fffu + ((ua >> 16) & 1u);
    ub += 0x7fffu + ((ub >> 16) & 1u);
    return (ua >> 16) | (ub & 0xffff0000u);
}
__device__ __forceinline__ unsigned short bf1(float a) {
    unsigned u = __float_as_uint(a);
    u += 0x7fffu + ((u >> 16) & 1u);
    return (unsigned short)(u >> 16);
}

// unpack a dwordx4 of 8 bf16 and accumulate into 8 fp32
__device__ __forceinline__ void acc8(float* a, uint4 v) {
    a[0] += __uint_as_float(v.x << 16);
    a[1] += __uint_as_float(v.x & 0xffff0000u);
    a[2] += __uint_as_float(v.y << 16);
    a[3] += __uint_as_float(v.y & 0xffff0000u);
    a[4] += __uint_as_float(v.z << 16);
    a[5] += __uint_as_float(v.z & 0xffff0000u);
    a[6] += __uint_as_float(v.w << 16);
    a[7] += __uint_as_float(v.w & 0xffff0000u);
}

// ---------------- weight prep: fp32 [k][n] -> bf16 [n][k] ----------------
__global__ __launch_bounds__(256) void k_prep(const float* __restrict__ W1,
                                              const float* __restrict__ W2,
                                              unsigned short* __restrict__ Wt1,
                                              unsigned short* __restrict__ Wt2) {
    int idx = blockIdx.x * 256 + threadIdx.x;
    if (idx < 128 * 128) {
        int k = idx >> 7, nn = idx & 127;
        Wt1[nn * 128 + k] = bf1(W1[idx]);
    }
    int i2 = idx - 128 * 128;
    if (i2 >= 0 && i2 < 128 * 64) {
        int k = i2 >> 6, nn = i2 & 63;
        Wt2[nn * 128 + k] = bf1(W2[i2]);
    }
}

// ---------------- CSR build (counting sort) ----------------

__global__ __launch_bounds__(256) void k_hist(const int* __restrict__ row,
                                              int* __restrict__ HT,
                                              int E, int nb, int nch) {
    __shared__ int h[512];
    int t = threadIdx.x, c = blockIdx.x;
    for (int i = t; i < nb; i += 256) h[i] = 0;
    __syncthreads();
    int base = c * CHUNK;
#pragma unroll
    for (int i = 0; i < CH_PT; ++i) {
        int e = base + i * 256 + t;
        if (e < E) atomicAdd(&h[row[e] >> BSH], 1);
    }
    __syncthreads();
    for (int i = t; i < nb; i += 256) HT[(size_t)i * nch + c] = h[i];
}

__global__ __launch_bounds__(256) void k_hscan_row(int* __restrict__ HT,
                                                   int* __restrict__ bsum,
                                                   int nch) {
    __shared__ int sh[256];
    int b = blockIdx.x, t = threadIdx.x;
    int carry = 0;
    for (int tile = 0; tile < nch; tile += 256) {
        int idx = tile + t;
        int v = (idx < nch) ? HT[(size_t)b * nch + idx] : 0;
        sh[t] = v;
        __syncthreads();
        for (int d = 1; d < 256; d <<= 1) {
            int u = (t >= d) ? sh[t - d] : 0;
            __syncthreads();
            sh[t] += u;
            __syncthreads();
        }
        if (idx < nch) HT[(size_t)b * nch + idx] = carry + sh[t] - v;
        carry += sh[255];
        __syncthreads();
    }
    if (t == 0) bsum[b] = carry;
}

__global__ __launch_bounds__(256) void k_hscan_base(const int* __restrict__ bsum,
                                                    int* __restrict__ bucketBase,
                                                    int nb, int E) {
    __shared__ int sh[256];
    int t = threadIdx.x;
    int v = (t < nb) ? bsum[t] : 0;
    sh[t] = v;
    __syncthreads();
    for (int d = 1; d < 256; d <<= 1) {
        int u = (t >= d) ? sh[t - d] : 0;
        __syncthreads();
        sh[t] += u;
        __syncthreads();
    }
    if (t < nb) bucketBase[t] = sh[t] - v;
    if (t == 0) bucketBase[nb] = E;
}

__global__ __launch_bounds__(256) void k_part(const int* __restrict__ row,
                                              const int* __restrict__ col,
                                              const int* __restrict__ HT,
                                              const int* __restrict__ bucketBase,
                                              int* __restrict__ packed,
                                              int E, int nb, int nch) {
    __shared__ int cur[512];
    int t = threadIdx.x, c = blockIdx.x;
    for (int i = t; i < nb; i += 256)
        cur[i] = HT[(size_t)i * nch + c] + bucketBase[i];
    __syncthreads();
    int base = c * CHUNK;
#pragma unroll
    for (int i = 0; i < CH_PT; ++i) {
        int e = base + i * 256 + t;
        if (e < E) {
            int r = row[e], cc = col[e];
            int b = r >> BSH;
            int pos = atomicAdd(&cur[b], 1);
            packed[pos] = ((r & LRM) << COLB) | cc;
        }
    }
}

__global__ __launch_bounds__(256) void k_build(const int* __restrict__ packed,
                                               const int* __restrict__ bucketBase,
                                               int* __restrict__ csr,
                                               int* __restrict__ offs,
                                               int* __restrict__ degc,
                                               float* __restrict__ invdeg,
                                               int N, int nb) {
    __shared__ int hist[512], scn[512], part[256];
    int t = threadIdx.x, b = blockIdx.x;
    int lo = bucketBase[b], hi = bucketBase[b + 1];
    int base_row = b << BSH;
    int nloc = N - base_row; if (nloc > 512) nloc = 512;
    hist[t] = 0; hist[t + 256] = 0;
    __syncthreads();
    for (int e = lo + t; e < hi; e += 256)
        atomicAdd(&hist[packed[e] >> COLB], 1);
    __syncthreads();
    int a = hist[2 * t], b2 = hist[2 * t + 1];
    part[t] = a + b2;
    __syncthreads();
    for (int d = 1; d < 256; d <<= 1) {
        int v = (t >= d) ? part[t - d] : 0;
        __syncthreads();
        part[t] += v;
        __syncthreads();
    }
    int bp = (t == 0) ? 0 : part[t - 1];
    scn[2 * t] = bp;
    scn[2 * t + 1] = bp + a;
    __syncthreads();
    for (int i = t; i < nloc; i += 256) {
        int r = base_row + i;
        offs[r] = lo + scn[i];
        int d = hist[i];
        degc[r] = d;
        invdeg[r] = 1.0f / (float)d;
    }
    __syncthreads();
    for (int e = lo + t; e < hi; e += 256) {
        int p = packed[e];
        int pos = lo + atomicAdd(&scn[p >> COLB], 1);
        csr[pos] = p & COLM;
    }
}

// ---------------- MFMA GEMMs ----------------

// h1b[n,128](bf16) = X @ W1. 256 thr, 64-row block; wave w: rows w*16..+15.
__global__ __launch_bounds__(256) void k_gemm1(const float* __restrict__ X,
                                               const unsigned short* __restrict__ Wt,
                                               unsigned short* __restrict__ H1b, int n) {
    __shared__ unsigned short xs[64][136];    // pitch 272B: 2-way-bank-safe b128
    __shared__ unsigned short wt[128][136];
    int tid = threadIdx.x;
    int r0 = blockIdx.x * 64;

    for (int i = tid; i < 64 * 32; i += 256) {
        int r = i >> 5, c4 = i & 31;
        float4 v = make_float4(0.f, 0.f, 0.f, 0.f);
        if (r0 + r < n) v = ((const float4*)X)[(size_t)(r0 + r) * 32 + c4];
        *(uint2*)&xs[r][c4 * 4] = make_uint2(bfpack(v.x, v.y), bfpack(v.z, v.w));
    }
    for (int i = tid; i < 128 * 16; i += 256) {
        int r = i >> 4, c = i & 15;
        *(uint4*)&wt[r][c * 8] = ((const uint4*)Wt)[r * 16 + c];
    }
    __syncthreads();

    int w = tid >> 6, lane = tid & 63;
    int ml = lane & 15, q = lane >> 4;
    floatx4 acc[8];
#pragma unroll
    for (int t = 0; t < 8; ++t) acc[t] = (floatx4)(0.f);

#pragma unroll
    for (int kc = 0; kc < 4; ++kc) {
        short8 af = *(const short8*)&xs[w * 16 + ml][kc * 32 + q * 8];
#pragma unroll
        for (int nt = 0; nt < 8; ++nt) {
            short8 bf = *(const short8*)&wt[nt * 16 + ml][kc * 32 + q * 8];
            acc[nt] = __builtin_amdgcn_mfma_f32_16x16x32_bf16(af, bf, acc[nt], 0, 0, 0);
        }
    }
#pragma unroll
    for (int nt = 0; nt < 8; ++nt)
#pragma unroll
        for (int r = 0; r < 4; ++r) {
            int rr = r0 + w * 16 + q * 4 + r;
            if (rr < n)
                H1b[(size_t)rr * 128 + nt * 16 + ml] = bf1(acc[nt][r]);
        }
}

// h2b[n,64](bf16) = h(bf16) @ W2. Same structure, N=64.
__global__ __launch_bounds__(256) void k_gemm2(const unsigned* __restrict__ Hin,
                                               const unsigned short* __restrict__ Wt,
                                               unsigned short* __restrict__ H2b, int n) {
    __shared__ unsigned short xs[64][136];
    __shared__ unsigned short wt[64][136];
    int tid = threadIdx.x;
    int r0 = blockIdx.x * 64;

    for (int i = tid; i < 64 * 16; i += 256) {
        int r = i >> 4, c = i & 15;
        uint4 v = make_uint4(0u, 0u, 0u, 0u);
        if (r0 + r < n) v = ((const uint4*)Hin)[(size_t)(r0 + r) * 16 + c];
        *(uint4*)&xs[r][c * 8] = v;
    }
    for (int i = tid; i < 64 * 16; i += 256) {
        int r = i >> 4, c = i & 15;
        *(uint4*)&wt[r][c * 8] = ((const uint4*)Wt)[r * 16 + c];
    }
    __syncthreads();

    int w = tid >> 6, lane = tid & 63;
    int ml = lane & 15, q = lane >> 4;
    floatx4 acc[4];
#pragma unroll
    for (int t = 0; t < 4; ++t) acc[t] = (floatx4)(0.f);

#pragma unroll
    for (int kc = 0; kc < 4; ++kc) {
        short8 af = *(const short8*)&xs[w * 16 + ml][kc * 32 + q * 8];
#pragma unroll
        for (int nt = 0; nt < 4; ++nt) {
            short8 bf = *(const short8*)&wt[nt * 16 + ml][kc * 32 + q * 8];
            acc[nt] = __builtin_amdgcn_mfma_f32_16x16x32_bf16(af, bf, acc[nt], 0, 0, 0);
        }
    }
#pragma unroll
    for (int nt = 0; nt < 4; ++nt)
#pragma unroll
        for (int r = 0; r < 4; ++r) {
            int rr = r0 + w * 16 + q * 4 + r;
            if (rr < n)
                H2b[(size_t)rr * 64 + nt * 16 + ml] = bf1(acc[nt][r]);
        }
}

// ---------------- Aggregations ----------------

// agg1: h[row](bf16) = relu((1/deg) * sum h1b[c]), D=128 (row = 16 uint4).
// Whole csr row loaded once (coalesced, lane<d) then distributed via shfl;
// 16 lanes cover one neighbor row; group g = lane>>4 takes neighbor i+g.
// Main loop 16 neighbors/iter = 4 dwordx4 gathers in flight.
// Tail: shfl is wave-uniform (clamped source lane) BEFORE the predicate —
// ds_bpermute reads from inactive lanes return 0 (the R11 bug).
__global__ __launch_bounds__(256) void k_agg1(const uint4* __restrict__ H1b,
                                              const int* __restrict__ offs,
                                              const int* __restrict__ degc,
                                              const float* __restrict__ invdeg,
                                              const int* __restrict__ csr,
                                              uint4* __restrict__ Hout, int n) {
    int wave = threadIdx.x >> 6, lane = threadIdx.x & 63;
    int row = blockIdx.x * 4 + wave;
    if (row >= n) return;
    int start = offs[row], d = degc[row];
    float inv = invdeg[row];
    int g = lane >> 4;       // neighbor slot 0..3
    int sl = lane & 15;      // 16B segment within row

    int nd = d < 64 ? d : 64;
    int idx = (lane < nd) ? csr[start + lane] : 0;

    float acc[8];
#pragma unroll
    for (int k = 0; k < 8; ++k) acc[k] = 0.f;

    int i = 0;
    for (; i + 16 <= nd; i += 16) {
        int c0 = __shfl(idx, i + g);
        int c1 = __shfl(idx, i + 4 + g);
        int c2 = __shfl(idx, i + 8 + g);
        int c3 = __shfl(idx, i + 12 + g);
        uint4 v0 = H1b[((unsigned)c0 << 4) + sl];
        uint4 v1 = H1b[((unsigned)c1 << 4) + sl];
        uint4 v2 = H1b[((unsigned)c2 << 4) + sl];
        uint4 v3 = H1b[((unsigned)c3 << 4) + sl];
        acc8(acc, v0);
        acc8(acc, v1);
        acc8(acc, v2);
        acc8(acc, v3);
    }
    for (; i < nd; i += 4) {
        int j = i + g;
        // all 64 lanes active at the shfl; clamp keeps source lane valid
        int c = __shfl(idx, (j < nd) ? j : 0);
        uint4 v = make_uint4(0u, 0u, 0u, 0u);
        if (j < nd) v = H1b[((unsigned)c << 4) + sl];
        acc8(acc, v);
    }
    for (; i < d; i += 4) {          // d > 64 fallback (rare)
        int j = i + g;
        uint4 v = make_uint4(0u, 0u, 0u, 0u);
        if (j < d) {
            int c = csr[start + j];
            v = H1b[((unsigned)c << 4) + sl];
        }
        acc8(acc, v);
    }

#pragma unroll
    for (int k = 0; k < 8; ++k) {
        acc[k] += __shfl_xor(acc[k], 16);
        acc[k] += __shfl_xor(acc[k], 32);
    }

    if (g == 0) {
#pragma unroll
        for (int k = 0; k < 8; ++k) acc[k] = fmaxf(acc[k] * inv, 0.f);
        uint4 o;
        o.x = bfpack(acc[0], acc[1]);
        o.y = bfpack(acc[2], acc[3]);
        o.z = bfpack(acc[4], acc[5]);
        o.w = bfpack(acc[6], acc[7]);
        Hout[(size_t)row * 16 + sl] = o;
    }
}

// agg2: Out[row](fp32) = (1/deg) * sum h2b[c], D=64 (row = 8 uint4).
// Same scheme; group g = lane>>3 (8 slots), 32 neighbors/iter = 4 gathers.
__global__ __launch_bounds__(256) void k_agg2(const uint4* __restrict__ H2b,
                                              const int* __restrict__ offs,
                                              const int* __restrict__ degc,
                                              const float* __restrict__ invdeg,
                                              const int* __restrict__ csr,
                                              float* __restrict__ Out, int n) {
    int wave = threadIdx.x >> 6, lane = threadIdx.x & 63;
    int row = blockIdx.x * 4 + wave;
    if (row >= n) return;
    int start = offs[row], d = degc[row];
    float inv = invdeg[row];
    int g = lane >> 3;       // neighbor slot 0..7
    int sl = lane & 7;       // 16B segment within row

    int nd = d < 64 ? d : 64;
    int idx = (lane < nd) ? csr[start + lane] : 0;

    float acc[8];
#pragma unroll
    for (int k = 0; k < 8; ++k) acc[k] = 0.f;

    int i = 0;
    for (; i + 32 <= nd; i += 32) {
        int c0 = __shfl(idx, i + g);
        int c1 = __shfl(idx, i + 8 + g);
        int c2 = __shfl(idx, i + 16 + g);
        int c3 = __shfl(idx, i + 24 + g);
        uint4 v0 = H2b[((unsigned)c0 << 3) + sl];
        uint4 v1 = H2b[((unsigned)c1 << 3) + sl];
        uint4 v2 = H2b[((unsigned)c2 << 3) + sl];
        uint4 v3 = H2b[((unsigned)c3 << 3) + sl];
        acc8(acc, v0);
        acc8(acc, v1);
        acc8(acc, v2);
        acc8(acc, v3);
    }
    for (; i + 16 <= nd; i += 16) {
        int c0 = __shfl(idx, i + g);
        int c1 = __shfl(idx, i + 8 + g);
        uint4 v0 = H2b[((unsigned)c0 << 3) + sl];
        uint4 v1 = H2b[((unsigned)c1 << 3) + sl];
        acc8(acc, v0);
        acc8(acc, v1);
    }
    for (; i < nd; i += 8) {
        int j = i + g;
        // all 64 lanes active at the shfl; clamp keeps source lane valid
        int c = __shfl(idx, (j < nd) ? j : 0);
        uint4 v = make_uint4(0u, 0u, 0u, 0u);
        if (j < nd) v = H2b[((unsigned)c << 3) + sl];
        acc8(acc, v);
    }
    for (; i < d; i += 8) {          // d > 64 fallback (rare)
        int j = i + g;
        uint4 v = make_uint4(0u, 0u, 0u, 0u);
        if (j < d) {
            int c = csr[start + j];
            v = H2b[((unsigned)c << 3) + sl];
        }
        acc8(acc, v);
    }

#pragma unroll
    for (int k = 0; k < 8; ++k) {
        acc[k] += __shfl_xor(acc[k], 8);
        acc[k] += __shfl_xor(acc[k], 16);
        acc[k] += __shfl_xor(acc[k], 32);
    }

    if (g == 0) {
        float4 o0, o1;
        o0.x = acc[0] * inv; o0.y = acc[1] * inv;
        o0.z = acc[2] * inv; o0.w = acc[3] * inv;
        o1.x = acc[4] * inv; o1.y = acc[5] * inv;
        o1.z = acc[6] * inv; o1.w = acc[7] * inv;
        ((float4*)Out)[(size_t)row * 16 + sl * 2]     = o0;
        ((float4*)Out)[(size_t)row * 16 + sl * 2 + 1] = o1;
    }
}

extern "C" void kernel_launch(void* const* d_in, const int* in_sizes, int n_in,
                              void* d_out, int out_size, void* d_ws, size_t ws_size,
                              hipStream_t stream) {
    const float* x    = (const float*)d_in[0];
    const float* W1   = (const float*)d_in[1];
    const float* W2   = (const float*)d_in[2];
    const int*   erow = (const int*)d_in[3];
    const int*   ecol = (const int*)d_in[4];
    const int N = in_sizes[0] / DIN;
    const int E = in_sizes[3];

    const int nb  = (N + (1 << BSH) - 1) >> BSH;   // 196 buckets
    const int nch = (E + CHUNK - 1) / CHUNK;       // 391 chunks

    size_t o = 0;
    auto take = [&](size_t nbytes) {
        void* p = (char*)d_ws + o;
        o += (nbytes + 255) & ~(size_t)255;
        return p;
    };
    int*            HT     = (int*)take((size_t)nb * nch * 4);
    int*            bsum   = (int*)take((size_t)nb * 4);
    int*            bbase  = (int*)take((size_t)(nb + 1) * 4);
    int*            packed = (int*)take((size_t)E * 4);
    int*            csr    = (int*)take((size_t)E * 4);
    int*            offs   = (int*)take((size_t)N * 4);
    int*            degc   = (int*)take((size_t)N * 4);
    float*          invdeg = (float*)take((size_t)N * 4);
    unsigned short* Wt1    = (unsigned short*)take(128 * 128 * 2);
    unsigned short* Wt2    = (unsigned short*)take(64 * 128 * 2);
    unsigned*       h1b    = (unsigned*)take((size_t)N * DH * 2);   // bf16
    unsigned*       h      = (unsigned*)take((size_t)N * DH * 2);   // bf16
    unsigned*       h2b    = h1b;   // reuses h1b (dead after agg1)

    k_prep      <<<96,  256, 0, stream>>>(W1, W2, Wt1, Wt2);
    k_hist      <<<nch, 256, 0, stream>>>(erow, HT, E, nb, nch);
    k_hscan_row <<<nb,  256, 0, stream>>>(HT, bsum, nch);
    k_hscan_base<<<1,   256, 0, stream>>>(bsum, bbase, nb, E);
    k_part      <<<nch, 256, 0, stream>>>(erow, ecol, HT, bbase, packed, E, nb, nch);
    k_build     <<<nb,  256, 0, stream>>>(packed, bbase, csr, offs, degc, invdeg, N, nb);
    k_gemm1<<<(N + 63) / 64, 256, 0, stream>>>(x, Wt1, (unsigned short*)h1b, N);
    k_agg1 <<<(N + 3) / 4, 256, 0, stream>>>((const uint4*)h1b, offs, degc, invdeg,
                                             csr, (uint4*)h, N);
    k_gemm2<<<(N + 63) / 64, 256, 0, stream>>>(h, Wt2, (unsigned short*)h2b, N);
    k_agg2 <<<(N + 3) / 4, 256, 0, stream>>>((const uint4*)h2b, offs, degc,
                                             invdeg, csr, (float*)d_out, N);
}